// Round 21
// baseline (78.864 us; speedup 1.0000x reference)
//
#include <hip/hip_runtime.h>

// CRF loss: A=8, S=200, B=64, T=32. scores (A,S,B,T,T) f32, targets (A,S,B) i32,
// mask (S,B) bool, a_mask (A,B) bool -- bool width (u8 vs i32) runtime-detected.
// Base = R20 (CHAMPION 73.0us). SUBTRACT-ONLY change: the consumer's
// shfl_xor(32) is DELETED from the recursion chain -- every lane redundantly
// computes the FULL 32-f sum (32 broadcast-friendly ds_read_b32 for e: lanes
// l and l+32 hit the SAME address = free broadcast, 32 t's cover all 32 banks
// = conflict-free; w via 8 broadcast float4 reads). Chain: w-read -> fma ->
// w-write (no cross-lane DS op). Everything else verbatim R20: producers own
// the gold path, renorm once per phase, raw lgkm barrier, runtime j-loop.
constexpr int A_ = 8, S_ = 200, B_ = 64, T_ = 32;
constexpr int START_TAG = 30, END_TAG = 31;
constexpr int NW = 8;                      // waves per block = tiles per phase
#define LOG2E 1.44269504088896340736f
#define LN2   0.69314718055994530942f

#if __has_builtin(__builtin_amdgcn_exp2f)
#define EXP2F(x) __builtin_amdgcn_exp2f(x)
#else
#define EXP2F(x) __expf((x) * LN2)
#endif

__device__ __forceinline__ int load_flag(const void* p, bool u8, int idx) {
    return u8 ? (int)((const unsigned char*)p)[idx] : ((const int*)p)[idx];
}

// LDS-writes-visible barrier WITHOUT vmcnt drain (proven R7/R12/R20).
#define LGKM_BARRIER do {                                                \
        asm volatile("s_waitcnt lgkmcnt(0)" ::: "memory");               \
        __builtin_amdgcn_s_barrier();                                    \
        asm volatile("" ::: "memory");                                   \
    } while (0)

__global__ __launch_bounds__(NW * 64)
void crf_loss_kernel(const float* __restrict__ scores,
                     const int* __restrict__ targets,
                     const void* __restrict__ mask,
                     const void* __restrict__ amask,
                     float* __restrict__ out)
{
    const int chain = blockIdx.x;          // 0..511
    const int a = chain >> 6;
    const int b = chain & (B_ - 1);
    const int tid = threadIdx.x;
    const int wv = tid >> 6;               // wave 0..7 (wave 0 also consumes)
    const int lane = tid & 63;
    const int t = lane & 31;

    // bool width detect: mask row 0 is all-true. int view: 1 -> int32, 0x01010101 -> uint8
    const bool bool_u8 = (((const int*)mask)[0] != 1);
    if (!load_flag(amask, bool_u8, a * B_ + b)) return;   // uniform block exit

    __shared__ __align__(16) float ebuf[2][NW][T_ * T_];  // 2 x 8 x 4KB exp-tiles
    __shared__ int tg_lds[S_];
    __shared__ float wlds[T_];                            // w vector (wave 0 only)
    __shared__ float gfin[NW];                            // per-wave gold sums

    // ---- first false mask index L (prefix mask) ----
    int L = S_;
    for (int base = 0; base < S_; base += 64) {
        int i = base + lane;
        int mv = (i < S_) ? load_flag(mask, bool_u8, i * B_ + b) : 1;
        unsigned long long bal = __ballot(mv == 0);
        if (bal != 0ull && L == S_) L = base + (int)__builtin_ctzll(bal);
    }

    for (int i = tid; i < S_; i += NW * 64)
        tg_lds[i] = targets[((size_t)a * S_ + i) * B_ + b];
    __syncthreads();                        // tg_lds ready (drain fine in prologue)

    const size_t s_stride = (size_t)B_ * T_ * T_;         // 65536 floats per step
    const float* cb = scores + ((size_t)a * S_ * B_ + b) * (T_ * T_);

    float wcur = 0.0f, C2 = 0.0f, tg0 = 0.0f;
    if (wv == 0) {                          // consumer init
        wcur = EXP2F(cb[START_TAG * T_ + t] * LOG2E);
        if (lane < 32) wlds[lane] = wcur;
        tg0 = cb[tg_lds[0]];                // gold score, step 0
    }
    float tgacc = 0.0f;                     // per-wave gold accumulation (uniform)

    const int nch = (L - 1 + NW - 1) / NW;  // phases (block-uniform)

#define E4(DST, SRC) do {                                                \
        DST.x = EXP2F(SRC.x * LOG2E); DST.y = EXP2F(SRC.y * LOG2E);      \
        DST.z = EXP2F(SRC.z * LOG2E); DST.w = EXP2F(SRC.w * LOG2E);      \
    } while (0)

#define RENORM do {                                                      \
        float m_ = wcur;                                                 \
        m_ = fmaxf(m_, __shfl_xor(m_, 1));                               \
        m_ = fmaxf(m_, __shfl_xor(m_, 2));                               \
        m_ = fmaxf(m_, __shfl_xor(m_, 4));                               \
        m_ = fmaxf(m_, __shfl_xor(m_, 8));                               \
        m_ = fmaxf(m_, __shfl_xor(m_, 16));                              \
        int eb_ = (__float_as_int(m_) >> 23) & 0xff;                     \
        C2 += (float)(eb_ - 127);                                        \
        float sc2_ = __int_as_float((254 - eb_) << 23);                  \
        wcur *= sc2_;                                                    \
        if (lane < 32) wlds[lane] = wcur;                                \
    } while (0)

#define TLOAD(Q0, Q1, Q2, Q3, GR, SC) do {                               \
        const int s_ = (SC);                                             \
        if (s_ < L) {                                                    \
            const float*  p_  = cb + (size_t)s_ * s_stride;              \
            const float4* p4_ = (const float4*)p_;                       \
            Q0 = p4_[lane];       Q1 = p4_[64 + lane];                   \
            Q2 = p4_[128 + lane]; Q3 = p4_[192 + lane];                  \
            GR = p_[tg_lds[s_]];                                         \
        }                                                                \
    } while (0)

    // consumer phase: runtime j-loop, FULL 32-f sum per lane (no cross-lane op
    // in the chain); one renorm per phase after the loop (pow2-exact).
#define CONSUME(KK) do {                                                 \
        const int kb_ = (KK) & 1;                                        \
        const int jmax_ = min(NW, L - 1 - (KK) * NW);                    \
        for (int j = 0; j < jmax_; ++j) {                                \
            const float* eb = &ebuf[kb_][j][0];                          \
            float e_[32];                                                \
            _Pragma("unroll")                                            \
            for (int i = 0; i < 32; ++i)                                 \
                e_[i] = eb[(i << 5) | t];                                \
            float4 w0_ = *(const float4*)&wlds[0];                       \
            float4 w1_ = *(const float4*)&wlds[4];                       \
            float4 w2_ = *(const float4*)&wlds[8];                       \
            float4 w3_ = *(const float4*)&wlds[12];                      \
            float4 w4_ = *(const float4*)&wlds[16];                      \
            float4 w5_ = *(const float4*)&wlds[20];                      \
            float4 w6_ = *(const float4*)&wlds[24];                      \
            float4 w7_ = *(const float4*)&wlds[28];                      \
            float s0_ = fmaf(e_[3], w0_.w, fmaf(e_[2], w0_.z,            \
                        fmaf(e_[1], w0_.y, e_[0] * w0_.x)));             \
            s0_ = fmaf(e_[7], w1_.w, fmaf(e_[6], w1_.z,                  \
                  fmaf(e_[5], w1_.y, fmaf(e_[4], w1_.x, s0_))));         \
            float s1_ = fmaf(e_[11], w2_.w, fmaf(e_[10], w2_.z,          \
                        fmaf(e_[9], w2_.y, e_[8] * w2_.x)));             \
            s1_ = fmaf(e_[15], w3_.w, fmaf(e_[14], w3_.z,                \
                  fmaf(e_[13], w3_.y, fmaf(e_[12], w3_.x, s1_))));       \
            float s2_ = fmaf(e_[19], w4_.w, fmaf(e_[18], w4_.z,          \
                        fmaf(e_[17], w4_.y, e_[16] * w4_.x)));           \
            s2_ = fmaf(e_[23], w5_.w, fmaf(e_[22], w5_.z,                \
                  fmaf(e_[21], w5_.y, fmaf(e_[20], w5_.x, s2_))));       \
            float s3_ = fmaf(e_[27], w6_.w, fmaf(e_[26], w6_.z,          \
                        fmaf(e_[25], w6_.y, e_[24] * w6_.x)));           \
            s3_ = fmaf(e_[31], w7_.w, fmaf(e_[30], w7_.z,                \
                  fmaf(e_[29], w7_.y, fmaf(e_[28], w7_.x, s3_))));       \
            float s_ = (s0_ + s1_) + (s2_ + s3_);                        \
            wcur = s_;                                                   \
            if (lane < 32) wlds[lane] = s_;                              \
        }                                                                \
        RENORM;                                                          \
    } while (0)

    // One phase with buffer set (Q0..Q3,GQ): exp-write chunk KK (+ accumulate
    // its gold score), refill the SAME regs with chunk KK+2, raw barrier,
    // wave-0 consume. No register rotation anywhere (proven R12/R20).
#define PHASE(Q0, Q1, Q2, Q3, GQ, KK) do {                               \
        const int k_ = (KK);                                             \
        const int scur_ = 1 + k_ * NW + wv;                              \
        if (scur_ < L) {                                                 \
            float4* ebw = (float4*)&ebuf[k_ & 1][wv][0];                 \
            float4 e0, e1, e2, e3;                                       \
            E4(e0, Q0); E4(e1, Q1); E4(e2, Q2); E4(e3, Q3);              \
            ebw[lane] = e0; ebw[64 + lane] = e1;                         \
            ebw[128 + lane] = e2; ebw[192 + lane] = e3;                  \
            tgacc += GQ;                                                 \
        }                                                                \
        TLOAD(Q0, Q1, Q2, Q3, GQ, scur_ + 2 * NW);                       \
        LGKM_BARRIER;                                                    \
        if (wv == 0) CONSUME(k_);                                        \
    } while (0)

    // ---- prologue prefetch: chunk 0 -> A, chunk 1 -> B ----
    float4 a0, a1, a2, a3, b0, b1, b2, b3;
    float ga = 0.0f, gb = 0.0f;
    TLOAD(a0, a1, a2, a3, ga, 1 + wv);
    TLOAD(b0, b1, b2, b3, gb, 1 + NW + wv);

    for (int k = 0; k < nch; k += 2) {
        PHASE(a0, a1, a2, a3, ga, k);
        if (k + 1 < nch)
            PHASE(b0, b1, b2, b3, gb, k + 1);
    }

    // ---- gold-path handoff: per-wave sums -> LDS -> wave 0 ----
    if (lane == 0) gfin[wv] = tgacc;
    __syncthreads();

    // ---- epilogue (consumer): logZ = ln(w[END_TAG]) + C2*ln2 ----
    if (wv == 0) {
        float tg = tg0;
#pragma unroll
        for (int w = 0; w < NW; ++w) tg += gfin[w];
        float wend = __shfl(wcur, END_TAG);
        float logZ = __logf(wend) + C2 * LN2;
        if (lane == 0)
            atomicAdd(out, (logZ - tg) * (1.0f / (float)B_));
    }
}

extern "C" void kernel_launch(void* const* d_in, const int* in_sizes, int n_in,
                              void* d_out, int out_size, void* d_ws, size_t ws_size,
                              hipStream_t stream) {
    const float* scores = (const float*)d_in[0];
    const int* targets  = (const int*)d_in[1];
    const void* mask    = d_in[2];
    const void* amask   = d_in[3];
    float* out = (float*)d_out;

    hipMemsetAsync(out, 0, sizeof(float), stream);
    crf_loss_kernel<<<dim3(A_ * B_), dim3(NW * 64), 0, stream>>>(
        scores, targets, mask, amask, out);
}